// Round 8
// baseline (196.100 us; speedup 1.0000x reference)
//
#include <hip/hip_runtime.h>
#include <hip/hip_bf16.h>

typedef __hip_bfloat16 bf16;
typedef short bf16x8 __attribute__((ext_vector_type(8)));
typedef float f32x4 __attribute__((ext_vector_type(4)));
typedef unsigned int u32;

static __device__ __forceinline__ float bfu2f(unsigned short u) { return __uint_as_float((u32)u << 16); }
static __device__ __forceinline__ u32 pack2(float a, float b) {
    return (u32)__bfloat16_as_ushort(__float2bfloat16(a))
         | ((u32)__bfloat16_as_ushort(__float2bfloat16(b)) << 16);
}
static __device__ __forceinline__ float wave_sum(float v) {
    #pragma unroll
    for (int off = 32; off > 0; off >>= 1) v += __shfl_xor(v, off);
    return v;
}

// async global->LDS 16B copy (wave-uniform LDS base + lane*16 by HW).
static __device__ __forceinline__ void gll16(const bf16* g, bf16* l) {
    __builtin_amdgcn_global_load_lds((const __attribute__((address_space(1))) void*)g,
                                     (__attribute__((address_space(3))) void*)l,
                                     16, 0, 0);
}

// ---------------------------------------------------------------------------
// Fused fp32->bf16 cast of Q, K, Wq, Wk, Wv, Wo. 4096 elems/block, 16/thread.
// ---------------------------------------------------------------------------
__global__ __launch_bounds__(256) void castall(const float* __restrict__ Q,  const float* __restrict__ K,
                                               const float* __restrict__ Wq, const float* __restrict__ Wk,
                                               const float* __restrict__ Wv, const float* __restrict__ Wo,
                                               bf16* __restrict__ dQ,  bf16* __restrict__ dK,
                                               bf16* __restrict__ dWq, bf16* __restrict__ dWk,
                                               bf16* __restrict__ dWv, bf16* __restrict__ dWo)
{
    const int b = blockIdx.x;
    const float* src; bf16* dst; size_t off;
    if (b < 1024)      { src = Q;  dst = dQ;  off = (size_t)b * 4096; }
    else if (b < 2048) { src = K;  dst = dK;  off = (size_t)(b - 1024) * 4096; }
    else {
        const int wb = b - 2048, wi = wb >> 6;
        off = (size_t)(wb & 63) * 4096;
        src = wi == 0 ? Wq : wi == 1 ? Wk : wi == 2 ? Wv : Wo;
        dst = wi == 0 ? dWq : wi == 1 ? dWk : wi == 2 ? dWv : dWo;
    }
    const size_t p = off + threadIdx.x * 16;
    const float4 v0 = *(const float4*)(src + p);
    const float4 v1 = *(const float4*)(src + p + 4);
    const float4 v2 = *(const float4*)(src + p + 8);
    const float4 v3 = *(const float4*)(src + p + 12);
    uint4 o0, o1;
    o0.x = pack2(v0.x, v0.y); o0.y = pack2(v0.z, v0.w);
    o0.z = pack2(v1.x, v1.y); o0.w = pack2(v1.z, v1.w);
    o1.x = pack2(v2.x, v2.y); o1.y = pack2(v2.z, v2.w);
    o1.z = pack2(v3.x, v3.y); o1.w = pack2(v3.z, v3.w);
    *(uint4*)(dst + p)     = o0;
    *(uint4*)(dst + p + 8) = o1;
}

// ---------------------------------------------------------------------------
// Fused QKV projection GEMM (NT), 128x128 tiles, grid (64, 12) = 768 blocks.
// DOUBLE-BUFFERED global_load_lds staging: prologue loads chunk 0; each iter
// issues chunk k+1 into buf^1 BEFORE computing buf (prefetch overlaps the
// whole compute phase; the barrier's vmcnt drain only catches stragglers).
// Unpadded [128][32] LDS, xor swizzle LDS[row][g]=glob[row][g^(row&3)].
// ---------------------------------------------------------------------------
__global__ __launch_bounds__(256) void gemm_qkv(const bf16* __restrict__ Aq, const bf16* __restrict__ Ak,
                                                const bf16* __restrict__ Wq, const bf16* __restrict__ Wk,
                                                const bf16* __restrict__ Wv,
                                                const float* __restrict__ bq, const float* __restrict__ bk,
                                                const float* __restrict__ bv,
                                                bf16* __restrict__ oQ, bf16* __restrict__ oK,
                                                bf16* __restrict__ oV)
{
    __shared__ bf16 As[2][128 * 32];
    __shared__ bf16 Bs[2][128 * 32];

    const int tid = threadIdx.x, lane = tid & 63, wave = tid >> 6;
    const int yy = blockIdx.y, wi = yy >> 2;
    const bf16* A     = wi == 0 ? Aq : Ak;
    const bf16* W     = wi == 0 ? Wq : wi == 1 ? Wk : Wv;
    const float* bias = wi == 0 ? bq : wi == 1 ? bk : bv;
    bf16* out         = wi == 0 ? oQ : wi == 1 ? oK : oV;
    const int mode    = wi == 2 ? 2 : 1;
    const int bm = blockIdx.x * 128;
    const int bn = (yy & 3) * 128;

    const int srow = tid >> 2;
    const int sg8  = (((tid & 3) ^ (srow & 3)) * 8);
    const int wm = (wave >> 1) * 64, wn = (wave & 1) * 64;
    const int fr = lane & 15, fq = lane >> 4;
    const int kqs = ((fq ^ (fr & 3)) * 8);

    f32x4 acc[4][4] = {};
    const bf16* Ap = A + (size_t)(bm + srow) * 512 + sg8;
    const bf16* Wp = W + (size_t)(bn + srow) * 512 + sg8;
    const int ld = 8 * tid;

    // prologue: chunk 0 -> buf 0
    gll16(Ap,                    As[0] + ld);
    gll16(Ap + (size_t)64 * 512, As[0] + 2048 + ld);
    gll16(Wp,                    Bs[0] + ld);
    gll16(Wp + (size_t)64 * 512, Bs[0] + 2048 + ld);

    int cur = 0;
    for (int k0 = 0; k0 < 512; k0 += 32) {
        __syncthreads();   // drains vmcnt -> buf[cur] ready; prev reads done
        if (k0 + 32 < 512) {
            const int nxt = cur ^ 1;
            gll16(Ap + k0 + 32,                    As[nxt] + ld);
            gll16(Ap + k0 + 32 + (size_t)64 * 512, As[nxt] + 2048 + ld);
            gll16(Wp + k0 + 32,                    Bs[nxt] + ld);
            gll16(Wp + k0 + 32 + (size_t)64 * 512, Bs[nxt] + 2048 + ld);
        }
        bf16x8 fa[4], fb[4];
        #pragma unroll
        for (int i = 0; i < 4; i++) {
            fa[i] = *(const bf16x8*)(&As[cur][(wm + 16 * i + fr) * 32 + kqs]);
            fb[i] = *(const bf16x8*)(&Bs[cur][(wn + 16 * i + fr) * 32 + kqs]);
        }
        #pragma unroll
        for (int i = 0; i < 4; i++)
            #pragma unroll
            for (int j = 0; j < 4; j++)
                acc[i][j] = __builtin_amdgcn_mfma_f32_16x16x32_bf16(fa[i], fb[j], acc[i][j], 0, 0, 0);
        cur ^= 1;
    }

    const int r0 = fq * 4;
    #pragma unroll
    for (int i = 0; i < 4; i++) {
        #pragma unroll
        for (int j = 0; j < 4; j++) {
            const int col = bn + wn + 16 * j + fr;
            const float bv2 = bias[col];
            #pragma unroll
            for (int r = 0; r < 4; r++) {
                const int row = bm + wm + 16 * i + r0 + r;
                const float v = acc[i][j][r] + bv2;
                const int b = row >> 10, n = row & 1023;
                const int h = col >> 6,  d = col & 63;
                size_t idx;
                if (mode == 1) idx = ((size_t)(b * 8 + h) * 1024 + n) * 64 + d;
                else           idx = ((size_t)(b * 8 + h) * 64 + d) * 1024 + n;
                out[idx] = __float2bfloat16(v);
            }
        }
    }
}

// ---------------------------------------------------------------------------
// O-projection GEMM (NT), 64x128 tiles, grid (128, 4) = 512 blocks.
// Same double-buffered async staging. 4 waves split N (wave tile 64x32).
// ---------------------------------------------------------------------------
__global__ __launch_bounds__(256) void gemm_o(const bf16* __restrict__ A,
                                              const bf16* __restrict__ W,
                                              const float* __restrict__ bias,
                                              bf16* __restrict__ out)
{
    __shared__ bf16 As[2][64 * 32];
    __shared__ bf16 Bs[2][128 * 32];

    const int tid = threadIdx.x, lane = tid & 63, wave = tid >> 6;
    const int bm = blockIdx.x * 64;
    const int bn = blockIdx.y * 128;

    const int srow = tid >> 2;
    const int sg8  = (((tid & 3) ^ (srow & 3)) * 8);
    const int wn = wave * 32;
    const int fr = lane & 15, fq = lane >> 4;
    const int kqs = ((fq ^ (fr & 3)) * 8);

    f32x4 acc[4][2] = {};
    const bf16* Ap = A + (size_t)(bm + srow) * 512 + sg8;
    const bf16* Wp = W + (size_t)(bn + srow) * 512 + sg8;
    const int ld = 8 * tid;

    gll16(Ap,                    As[0] + ld);
    gll16(Wp,                    Bs[0] + ld);
    gll16(Wp + (size_t)64 * 512, Bs[0] + 2048 + ld);

    int cur = 0;
    for (int k0 = 0; k0 < 512; k0 += 32) {
        __syncthreads();
        if (k0 + 32 < 512) {
            const int nxt = cur ^ 1;
            gll16(Ap + k0 + 32,                    As[nxt] + ld);
            gll16(Wp + k0 + 32,                    Bs[nxt] + ld);
            gll16(Wp + k0 + 32 + (size_t)64 * 512, Bs[nxt] + 2048 + ld);
        }
        bf16x8 fa[4], fb[2];
        #pragma unroll
        for (int i = 0; i < 4; i++)
            fa[i] = *(const bf16x8*)(&As[cur][(16 * i + fr) * 32 + kqs]);
        #pragma unroll
        for (int j = 0; j < 2; j++)
            fb[j] = *(const bf16x8*)(&Bs[cur][(wn + 16 * j + fr) * 32 + kqs]);
        #pragma unroll
        for (int i = 0; i < 4; i++)
            #pragma unroll
            for (int j = 0; j < 2; j++)
                acc[i][j] = __builtin_amdgcn_mfma_f32_16x16x32_bf16(fa[i], fb[j], acc[i][j], 0, 0, 0);
        cur ^= 1;
    }

    const int r0 = fq * 4;
    #pragma unroll
    for (int i = 0; i < 4; i++) {
        #pragma unroll
        for (int j = 0; j < 2; j++) {
            const int col = bn + wn + 16 * j + fr;
            const float bv = bias[col];
            #pragma unroll
            for (int r = 0; r < 4; r++) {
                const int row = bm + 16 * i + r0 + r;
                out[(size_t)row * 512 + col] = __float2bfloat16(acc[i][j][r] + bv);
            }
        }
    }
}

// ---------------------------------------------------------------------------
// MFMA flash attention — S^T form, fixed-max softmax, DOUBLE-BUFFERED async
// K/V staging (prefetch chunk kt+1 before computing kt; ONE barrier/chunk).
// Ks/Vs unpadded [64][64], xor swizzle LDS[row][g]=glob[row][g^(row&7)].
// Qh [b,h,n,64], Kh [b,h,m,64], VhT [b,h,d,m]. Block 256/4 waves,
// wave = 16 q-rows, grid (16, 64).
// ---------------------------------------------------------------------------
__global__ __launch_bounds__(256) void attn_mfma(const bf16* __restrict__ Qh,
                                                 const bf16* __restrict__ Kh,
                                                 const bf16* __restrict__ VhT,
                                                 bf16* __restrict__ Oc)
{
    __shared__ bf16 Ks[2][64 * 64];
    __shared__ bf16 Vs[2][64 * 64];
    __shared__ bf16 Ps[4][16 * 72];

    const int tid = threadIdx.x, lane = tid & 63, w = tid >> 6;
    const int bh = blockIdx.y;
    const int wq = blockIdx.x * 64 + w * 16;

    const bf16* Qb = Qh  + ((size_t)bh * 1024 + wq) * 64;
    const bf16* Kb = Kh  + (size_t)bh * 1024 * 64;
    const bf16* Vb = VhT + (size_t)bh * 64 * 1024;

    const int fl = lane & 15, fq = lane >> 4;
    const int flk = fl & 7;
    const int gA = (fq ^ flk) * 8;
    const int gB = ((4 | fq) ^ flk) * 8;

    bf16x8 qf0 = *(const bf16x8*)(Qb + fl * 64 + fq * 8);
    bf16x8 qf1 = *(const bf16x8*)(Qb + fl * 64 + 32 + fq * 8);

    f32x4 o[4] = {};
    float lsum = 0.f;
    const float sc2 = 0.04419417382415922f * 1.4426950408889634f; // /sqrt(512)*log2e

    const int srow = tid >> 3;
    const int sg8  = (((tid & 7) ^ (srow & 7)) * 8);
    const bf16* KbR  = Kb + (size_t)srow * 64 + sg8;
    const bf16* VbR0 = Vb + (size_t)srow * 1024 + sg8;
    const bf16* VbR1 = Vb + (size_t)(srow + 32) * 1024 + sg8;
    const int ld = 8 * tid;

    // prologue: chunk 0 -> buf 0
    gll16(KbR,               Ks[0] + ld);
    gll16(KbR + 32 * 64,     Ks[0] + 2048 + ld);
    gll16(VbR0,              Vs[0] + ld);
    gll16(VbR1,              Vs[0] + 2048 + ld);

    int cur = 0;
    for (int kt = 0; kt < 16; kt++) {
        __syncthreads();   // buf[cur] ready (vmcnt drain); prev reads done
        if (kt < 15) {
            const int nxt = cur ^ 1;
            const int m1 = (kt + 1) * 64;
            gll16(KbR + (size_t)m1 * 64,        Ks[nxt] + ld);
            gll16(KbR + (size_t)(m1 + 32) * 64, Ks[nxt] + 2048 + ld);
            gll16(VbR0 + m1,                    Vs[nxt] + ld);
            gll16(VbR1 + m1,                    Vs[nxt] + 2048 + ld);
        }

        // S^T = K Q^T
        f32x4 st[4] = {};
        #pragma unroll
        for (int tm = 0; tm < 4; tm++) {
            bf16x8 kf0 = *(const bf16x8*)(&Ks[cur][(16 * tm + fl) * 64 + gA]);
            bf16x8 kf1 = *(const bf16x8*)(&Ks[cur][(16 * tm + fl) * 64 + gB]);
            st[tm] = __builtin_amdgcn_mfma_f32_16x16x32_bf16(kf0, qf0, st[tm], 0, 0, 0);
            st[tm] = __builtin_amdgcn_mfma_f32_16x16x32_bf16(kf1, qf1, st[tm], 0, 0, 0);
        }

        // p = exp2(s*sc2); per-lane l accumulation; pack P^T to per-wave LDS
        #pragma unroll
        for (int tm = 0; tm < 4; tm++) {
            float p0 = __builtin_amdgcn_exp2f(st[tm][0] * sc2);
            float p1 = __builtin_amdgcn_exp2f(st[tm][1] * sc2);
            float p2 = __builtin_amdgcn_exp2f(st[tm][2] * sc2);
            float p3 = __builtin_amdgcn_exp2f(st[tm][3] * sc2);
            lsum += (p0 + p1) + (p2 + p3);
            uint2 pk;
            pk.x = pack2(p0, p1);
            pk.y = pack2(p2, p3);
            *(uint2*)(&Ps[w][fl * 72 + 16 * tm + fq * 4]) = pk;
        }

        // O^T += V^T P^T
        bf16x8 pf0 = *(const bf16x8*)(&Ps[w][fl * 72 + fq * 8]);
        bf16x8 pf1 = *(const bf16x8*)(&Ps[w][fl * 72 + 32 + fq * 8]);
        #pragma unroll
        for (int jd = 0; jd < 4; jd++) {
            bf16x8 vf0 = *(const bf16x8*)(&Vs[cur][(16 * jd + fl) * 64 + gA]);
            bf16x8 vf1 = *(const bf16x8*)(&Vs[cur][(16 * jd + fl) * 64 + gB]);
            o[jd] = __builtin_amdgcn_mfma_f32_16x16x32_bf16(vf0, pf0, o[jd], 0, 0, 0);
            o[jd] = __builtin_amdgcn_mfma_f32_16x16x32_bf16(vf1, pf1, o[jd], 0, 0, 0);
        }
        cur ^= 1;
    }

    lsum += __shfl_xor(lsum, 16);
    lsum += __shfl_xor(lsum, 32);
    const float linv = 1.f / lsum;

    const int b = bh >> 3, h = bh & 7;
    const size_t obase = ((size_t)(b * 1024 + wq + fl)) * 512 + h * 64;
    #pragma unroll
    for (int jd = 0; jd < 4; jd++) {
        const ushort4 qr = *(const ushort4*)(Qb + fl * 64 + 16 * jd + fq * 4);
        const float v0 = o[jd][0] * linv + bfu2f(qr.x);
        const float v1 = o[jd][1] * linv + bfu2f(qr.y);
        const float v2 = o[jd][2] * linv + bfu2f(qr.z);
        const float v3 = o[jd][3] * linv + bfu2f(qr.w);
        uint2 w2;
        w2.x = pack2(v0, v1);
        w2.y = pack2(v2, v3);
        *(uint2*)(&Oc[obase + 16 * jd + fq * 4]) = w2;
    }
}

// ---------------------------------------------------------------------------
// LayerNorm over rows of 512 — wave/row, 8 consecutive elems/lane.
// ---------------------------------------------------------------------------
__global__ __launch_bounds__(256) void ln0(const bf16* __restrict__ X,
                                           const float* __restrict__ g,
                                           const float* __restrict__ be,
                                           bf16* __restrict__ Y)
{
    const int lane = threadIdx.x & 63;
    const int row = blockIdx.x * 4 + (threadIdx.x >> 6);
    const size_t base = (size_t)row * 512 + lane * 8;
    const bf16x8 xv = *(const bf16x8*)(X + base);
    float x[8];
    #pragma unroll
    for (int j = 0; j < 8; j++) x[j] = bfu2f((unsigned short)xv[j]);
    float s = 0.f, s2 = 0.f;
    #pragma unroll
    for (int j = 0; j < 8; j++) { s += x[j]; s2 += x[j] * x[j]; }
    s = wave_sum(s); s2 = wave_sum(s2);
    const float mean = s * (1.f / 512.f);
    const float var = s2 * (1.f / 512.f) - mean * mean;
    const float rs = rsqrtf(fmaxf(var, 0.f) + 1e-5f);
    const float4 gv0 = *(const float4*)(g + lane * 8);
    const float4 gv1 = *(const float4*)(g + lane * 8 + 4);
    const float4 bv0 = *(const float4*)(be + lane * 8);
    const float4 bv1 = *(const float4*)(be + lane * 8 + 4);
    uint4 ov;
    ov.x = pack2((x[0]-mean)*rs*gv0.x + bv0.x, (x[1]-mean)*rs*gv0.y + bv0.y);
    ov.y = pack2((x[2]-mean)*rs*gv0.z + bv0.z, (x[3]-mean)*rs*gv0.w + bv0.w);
    ov.z = pack2((x[4]-mean)*rs*gv1.x + bv1.x, (x[5]-mean)*rs*gv1.y + bv1.y);
    ov.w = pack2((x[6]-mean)*rs*gv1.z + bv1.z, (x[7]-mean)*rs*gv1.w + bv1.w);
    *(uint4*)(Y + base) = ov;
}

__global__ __launch_bounds__(256) void ln1(const bf16* __restrict__ X,
                                           const bf16* __restrict__ R,
                                           const float* __restrict__ g,
                                           const float* __restrict__ be,
                                           float* __restrict__ Y)
{
    const int lane = threadIdx.x & 63;
    const int row = blockIdx.x * 4 + (threadIdx.x >> 6);
    const size_t base = (size_t)row * 512 + lane * 8;
    const bf16x8 xv = *(const bf16x8*)(X + base);
    const bf16x8 rv = *(const bf16x8*)(R + base);
    float x[8];
    #pragma unroll
    for (int j = 0; j < 8; j++)
        x[j] = bfu2f((unsigned short)rv[j]) + fmaxf(bfu2f((unsigned short)xv[j]), 0.f);
    float s = 0.f, s2 = 0.f;
    #pragma unroll
    for (int j = 0; j < 8; j++) { s += x[j]; s2 += x[j] * x[j]; }
    s = wave_sum(s); s2 = wave_sum(s2);
    const float mean = s * (1.f / 512.f);
    const float var = s2 * (1.f / 512.f) - mean * mean;
    const float rs = rsqrtf(fmaxf(var, 0.f) + 1e-5f);
    const float4 gv0 = *(const float4*)(g + lane * 8);
    const float4 gv1 = *(const float4*)(g + lane * 8 + 4);
    const float4 bv0 = *(const float4*)(be + lane * 8);
    const float4 bv1 = *(const float4*)(be + lane * 8 + 4);
    float4 y0, y1;
    y0.x = (x[0]-mean)*rs*gv0.x + bv0.x; y0.y = (x[1]-mean)*rs*gv0.y + bv0.y;
    y0.z = (x[2]-mean)*rs*gv0.z + bv0.z; y0.w = (x[3]-mean)*rs*gv0.w + bv0.w;
    y1.x = (x[4]-mean)*rs*gv1.x + bv1.x; y1.y = (x[5]-mean)*rs*gv1.y + bv1.y;
    y1.z = (x[6]-mean)*rs*gv1.z + bv1.z; y1.w = (x[7]-mean)*rs*gv1.w + bv1.w;
    *(float4*)(Y + base)     = y0;
    *(float4*)(Y + base + 4) = y1;
}

// ---------------------------------------------------------------------------
extern "C" void kernel_launch(void* const* d_in, const int* in_sizes, int n_in,
                              void* d_out, int out_size, void* d_ws, size_t ws_size,
                              hipStream_t stream)
{
    const float* Q   = (const float*)d_in[0];
    const float* K   = (const float*)d_in[1];
    const float* Wq  = (const float*)d_in[2];
    const float* bq  = (const float*)d_in[3];
    const float* Wk  = (const float*)d_in[4];
    const float* bk  = (const float*)d_in[5];
    const float* Wv  = (const float*)d_in[6];
    const float* bv  = (const float*)d_in[7];
    const float* Wo  = (const float*)d_in[8];
    const float* bo  = (const float*)d_in[9];
    const float* g0  = (const float*)d_in[10];
    const float* be0 = (const float*)d_in[11];
    const float* g1  = (const float*)d_in[12];
    const float* be1 = (const float*)d_in[13];
    float* out = (float*)d_out;

    const size_t NQK = (size_t)8 * 1024 * 512;  // 4M
    const size_t NW  = (size_t)512 * 512;       // 256K
    bf16* ws   = (bf16*)d_ws;
    bf16* cQ   = ws;
    bf16* cK   = cQ + NQK;
    bf16* cWq  = cK + NQK;
    bf16* cWk  = cWq + NW;
    bf16* cWv  = cWk + NW;
    bf16* cWo  = cWv + NW;
    bf16* pQh  = cWo + NW;           // [b,h,n,d]
    bf16* pKh  = pQh + NQK;          // [b,h,m,d]
    bf16* pVhT = pKh + NQK;          // [b,h,d,m]
    bf16* pOc  = (bf16*)d_out;       // attn output staged in d_out
    bf16* pO1  = pKh;                // Kh dead after attn
    bf16* pTmp = pQh;                // Qh dead after attn

    castall<<<2304, 256, 0, stream>>>(Q, K, Wq, Wk, Wv, Wo, cQ, cK, cWq, cWk, cWv, cWo);
    gemm_qkv<<<dim3(64, 12), 256, 0, stream>>>(cQ, cK, cWq, cWk, cWv, bq, bk, bv, pQh, pKh, pVhT);
    attn_mfma<<<dim3(16, 64), 256, 0, stream>>>(pQh, pKh, pVhT, pOc);
    ln0<<<2048, 256, 0, stream>>>(pOc, g0, be0, pO1);
    gemm_o<<<dim3(128, 4), 256, 0, stream>>>(pO1, cWo, bo, pTmp);
    ln1<<<2048, 256, 0, stream>>>(pTmp, pO1, g1, be1, out);
}